// Round 13
// baseline (47.986 us; speedup 1.0000x reference)
//
#include <hip/hip_runtime.h>
#include <math.h>

#define HH 96
#define WW 96
#define NPIX (HH*WW)          // 9216
#define CC 320
#define GG 32
#define CPG 10                // channels per group
#define YT 3                  // y-tiles per image (32 rows each)
#define TPB 256               // 4 waves; thread = (r=tid>>5, xcl=tid&31), 2 row-pairs

// ---------------------------------------------------------------------------
// Kernel 1 (single pass over x): block = (b, group, ytile of 32 rows).
// Grid = 16*32*3 = 1536 blocks x 4 waves = 6144 waves = exactly 6 blocks/CU
// -> single dispatch round, no half-empty tail (R11 had 12288 waves = 1.5
// rounds). Thread (r,xcl) owns TWO row-pairs: Y0a=yt*32+2r and Y0b=Y0a+16,
// pixels [3*xcl, 3*xcl+3) (3 px/lane x 32 lanes = full row, 100% lanes).
// Per channel: 8 float3 row loads (more MLP per wave), halo via shfl,
// 3x3 conv for 12 px, accumulating
//   p[j]  += (proj_w*gn_w)[c] * u            (stats-independent plane)
//   s1,s2 += h, h^2  with h = u + dw_b[c]    (GN statistics)
// P stays fp32 with float3 stores (12-byte struct, exact stores).
// NOTE: fp16 ext_vector_type(3) is 8-byte-padded -> overlapping stores
// corrupted neighbors in R12. Bytes are non-binding anyway (R4-R6).
// ---------------------------------------------------------------------------
__global__ __launch_bounds__(TPB, 6)
void k_main(const float* __restrict__ x, const float* __restrict__ dw_w,
            const float* __restrict__ dw_b, const float* __restrict__ gn_w,
            const float* __restrict__ proj_w,
            float* __restrict__ P, float* __restrict__ partials) {
  const int bid = blockIdx.x;
  const int yt = bid % YT;
  const int t  = bid / YT;
  const int gr = t & 31;
  const int b  = t >> 5;

  __shared__ float wsm[CPG * 9], ssm[CPG], bsm[CPG];
  const int tid = threadIdx.x;
  if (tid < CPG * 9) wsm[tid] = dw_w[gr * CPG * 9 + tid];
  if (tid < CPG) {
    int c = gr * CPG + tid;
    ssm[tid] = proj_w[c] * gn_w[c];
    bsm[tid] = dw_b[c];
  }
  __syncthreads();

  const int lane = tid & 63;
  const int xcl  = tid & 31;            // 0..31, ALL active
  const int r    = tid >> 5;            // 0..7
  const int col0 = 3 * xcl;
  const int Y0a = yt * 32 + 2 * r;      // pair a rows Y0a, Y0a+1
  const int Y0b = Y0a + 16;             // pair b rows Y0b, Y0b+1

  const float mtopa = (Y0a > 0) ? 1.f : 0.f;
  const float mbotb = (Y0b + 1 < HH - 1) ? 1.f : 0.f;
  const int ya  = max(Y0a - 1, 0);
  const int ydb = min(Y0b + 2, HH - 1);
  const float mlft = (xcl > 0)  ? 1.f : 0.f;
  const float mrgt = (xcl < 31) ? 1.f : 0.f;
  const int lm1 = (xcl >= 1) ? lane - 1 : lane;
  const int lp1 = (xcl < 31) ? lane + 1 : lane;

  const int offa0 = ya * WW + col0;              // pair a rows
  const int offb0 = Y0a * WW + col0;
  const int offc0 = (Y0a + 1) * WW + col0;
  const int offd0 = (Y0a + 2) * WW + col0;
  const int offa1 = (Y0b - 1) * WW + col0;       // pair b rows
  const int offb1 = Y0b * WW + col0;
  const int offc1 = (Y0b + 1) * WW + col0;
  const int offd1 = ydb * WW + col0;
  const float* xg = x + ((size_t)(b * CC + gr * CPG)) * NPIX;

  float p0=0.f,p1=0.f,p2=0.f,p3=0.f,p4=0.f,p5=0.f;
  float p6=0.f,p7=0.f,p8=0.f,p9=0.f,p10=0.f,p11=0.f;
  float s1 = 0.f, s2 = 0.f;

  #pragma unroll 1
  for (int ch = 0; ch < CPG; ++ch) {
    const float* img = xg + ch * NPIX;
    float3 A0 = *(const float3*)(img + offa0);
    float3 B0 = *(const float3*)(img + offb0);
    float3 C0 = *(const float3*)(img + offc0);
    float3 D0 = *(const float3*)(img + offd0);
    float3 A1 = *(const float3*)(img + offa1);
    float3 B1 = *(const float3*)(img + offb1);
    float3 C1 = *(const float3*)(img + offc1);
    float3 D1 = *(const float3*)(img + offd1);
    A0.x *= mtopa; A0.y *= mtopa; A0.z *= mtopa;
    D1.x *= mbotb; D1.y *= mbotb; D1.z *= mbotb;

    // halo pixels from wave neighbors
    float La0 = __shfl(A0.z, lm1) * mlft, Ta0 = __shfl(A0.x, lp1) * mrgt;
    float Lb0 = __shfl(B0.z, lm1) * mlft, Tb0 = __shfl(B0.x, lp1) * mrgt;
    float Lc0 = __shfl(C0.z, lm1) * mlft, Tc0 = __shfl(C0.x, lp1) * mrgt;
    float Ld0 = __shfl(D0.z, lm1) * mlft, Td0 = __shfl(D0.x, lp1) * mrgt;
    float La1 = __shfl(A1.z, lm1) * mlft, Ta1 = __shfl(A1.x, lp1) * mrgt;
    float Lb1 = __shfl(B1.z, lm1) * mlft, Tb1 = __shfl(B1.x, lp1) * mrgt;
    float Lc1 = __shfl(C1.z, lm1) * mlft, Tc1 = __shfl(C1.x, lp1) * mrgt;
    float Ld1 = __shfl(D1.z, lm1) * mlft, Td1 = __shfl(D1.x, lp1) * mrgt;

    const float* wp = &wsm[ch * 9];
    const float w0 = wp[0], w1 = wp[1], w2 = wp[2];
    const float w3 = wp[3], w4 = wp[4], w5 = wp[5];
    const float w6 = wp[6], w7 = wp[7], w8 = wp[8];
    const float sc = ssm[ch], bias = bsm[ch];

    // pair a, row Y0a (A0,B0,C0) and row Y0a+1 (B0,C0,D0)
    float u0 = w0*La0  + w1*A0.x + w2*A0.y + w3*Lb0  + w4*B0.x + w5*B0.y + w6*Lc0  + w7*C0.x + w8*C0.y;
    float u1 = w0*A0.x + w1*A0.y + w2*A0.z + w3*B0.x + w4*B0.y + w5*B0.z + w6*C0.x + w7*C0.y + w8*C0.z;
    float u2 = w0*A0.y + w1*A0.z + w2*Ta0  + w3*B0.y + w4*B0.z + w5*Tb0  + w6*C0.y + w7*C0.z + w8*Tc0;
    float u3 = w0*Lb0  + w1*B0.x + w2*B0.y + w3*Lc0  + w4*C0.x + w5*C0.y + w6*Ld0  + w7*D0.x + w8*D0.y;
    float u4 = w0*B0.x + w1*B0.y + w2*B0.z + w3*C0.x + w4*C0.y + w5*C0.z + w6*D0.x + w7*D0.y + w8*D0.z;
    float u5 = w0*B0.y + w1*B0.z + w2*Tb0  + w3*C0.y + w4*C0.z + w5*Tc0  + w6*D0.y + w7*D0.z + w8*Td0;
    // pair b
    float u6 = w0*La1  + w1*A1.x + w2*A1.y + w3*Lb1  + w4*B1.x + w5*B1.y + w6*Lc1  + w7*C1.x + w8*C1.y;
    float u7 = w0*A1.x + w1*A1.y + w2*A1.z + w3*B1.x + w4*B1.y + w5*B1.z + w6*C1.x + w7*C1.y + w8*C1.z;
    float u8 = w0*A1.y + w1*A1.z + w2*Ta1  + w3*B1.y + w4*B1.z + w5*Tb1  + w6*C1.y + w7*C1.z + w8*Tc1;
    float u9 = w0*Lb1  + w1*B1.x + w2*B1.y + w3*Lc1  + w4*C1.x + w5*C1.y + w6*Ld1  + w7*D1.x + w8*D1.y;
    float u10= w0*B1.x + w1*B1.y + w2*B1.z + w3*C1.x + w4*C1.y + w5*C1.z + w6*D1.x + w7*D1.y + w8*D1.z;
    float u11= w0*B1.y + w1*B1.z + w2*Tb1  + w3*C1.y + w4*C1.z + w5*Tc1  + w6*D1.y + w7*D1.z + w8*Td1;

    p0 = fmaf(sc, u0, p0);  p1 = fmaf(sc, u1, p1);  p2 = fmaf(sc, u2, p2);
    p3 = fmaf(sc, u3, p3);  p4 = fmaf(sc, u4, p4);  p5 = fmaf(sc, u5, p5);
    p6 = fmaf(sc, u6, p6);  p7 = fmaf(sc, u7, p7);  p8 = fmaf(sc, u8, p8);
    p9 = fmaf(sc, u9, p9);  p10= fmaf(sc, u10,p10); p11= fmaf(sc, u11,p11);

    float h0 = u0 + bias, h1 = u1 + bias, h2 = u2 + bias;
    float h3 = u3 + bias, h4 = u4 + bias, h5 = u5 + bias;
    float h6 = u6 + bias, h7 = u7 + bias, h8 = u8 + bias;
    float h9 = u9 + bias, h10= u10+ bias, h11= u11+ bias;
    s1 += (((h0 + h1) + (h2 + h3)) + ((h4 + h5) + (h6 + h7)))
        + (((h8 + h9) + (h10 + h11)));
    float q0 = fmaf(h0, h0, h1 * h1),  q1 = fmaf(h2, h2, h3 * h3);
    float q2 = fmaf(h4, h4, h5 * h5),  q3 = fmaf(h6, h6, h7 * h7);
    float q4 = fmaf(h8, h8, h9 * h9),  q5 = fmaf(h10,h10,h11 * h11);
    s2 += ((q0 + q1) + (q2 + q3)) + (q4 + q5);
  }

  {
    float* Pp = P + ((size_t)(b * GG + gr)) * NPIX;
    float3 v;
    v.x = p0;  v.y = p1;  v.z = p2;  *(float3*)&Pp[offb0] = v;
    v.x = p3;  v.y = p4;  v.z = p5;  *(float3*)&Pp[offc0] = v;
    v.x = p6;  v.y = p7;  v.z = p8;  *(float3*)&Pp[offb1] = v;
    v.x = p9;  v.y = p10; v.z = p11; *(float3*)&Pp[offc1] = v;
  }

  // block-reduce s1,s2 (4 waves)
  #pragma unroll
  for (int off = 32; off; off >>= 1) {
    s1 += __shfl_down(s1, off);
    s2 += __shfl_down(s2, off);
  }
  __shared__ float r1[4], r2[4];
  if ((tid & 63) == 0) { r1[tid >> 6] = s1; r2[tid >> 6] = s2; }
  __syncthreads();
  if (tid == 0) {
    partials[bid * 2]     = r1[0] + r1[1] + r1[2] + r1[3];
    partials[bid * 2 + 1] = r2[0] + r2[1] + r2[2] + r2[3];
  }
}

// ---------------------------------------------------------------------------
// Kernel 2: fused coef + output. Each block (9 per batch) recomputes its
// batch's 32 rinv values + scalar D from partials, then
// out[b,p] = sigmoid( sum_g rinv[g]*P[b,g,p] + D ).  256 thr, 4 px/thread.
// ---------------------------------------------------------------------------
__global__ __launch_bounds__(256)
void k_out(const float* __restrict__ P, const float* __restrict__ partials,
           const float* __restrict__ dw_b, const float* __restrict__ gn_w,
           const float* __restrict__ gn_b, const float* __restrict__ proj_w,
           const float* __restrict__ proj_b, float* __restrict__ out) {
  const int b   = blockIdx.x / 9;
  const int blk = blockIdx.x % 9;
  __shared__ float rs[GG];
  __shared__ float Ds;

  if (threadIdx.x < GG) {
    const int gr = threadIdx.x;
    float s1 = 0.f, s2 = 0.f;
    #pragma unroll
    for (int t = 0; t < YT; ++t) {
      int o = (((b * GG + gr) * YT) + t) * 2;
      s1 += partials[o];
      s2 += partials[o + 1];
    }
    const float invN = 1.f / (float)(CPG * NPIX);
    float mean = s1 * invN;
    float var  = s2 * invN - mean * mean;
    float rinv = rsqrtf(var + 1e-5f);
    rs[gr] = rinv;
    float K = 0.f, E = 0.f;
    #pragma unroll
    for (int i = 0; i < CPG; ++i) {
      int c = gr * CPG + i;
      float pg = proj_w[c] * gn_w[c];
      K = fmaf(pg, dw_b[c] - mean, K);
      E = fmaf(proj_w[c], gn_b[c], E);
    }
    float contrib = fmaf(rinv, K, E);
    #pragma unroll
    for (int m = 16; m; m >>= 1) contrib += __shfl_xor(contrib, m, 32);
    if (gr == 0) Ds = contrib + proj_b[0];
  }
  __syncthreads();

  const int p = (blk * 256 + threadIdx.x) * 4;    // 9*256*4 = 9216
  const float* Pb = P + (size_t)b * GG * NPIX + p;
  float g0 = 0.f, g1 = 0.f, g2 = 0.f, g3 = 0.f;
  #pragma unroll
  for (int gr = 0; gr < GG; ++gr) {
    float4 v = *(const float4*)(Pb + (size_t)gr * NPIX);
    float rr = rs[gr];
    g0 = fmaf(rr, v.x, g0);
    g1 = fmaf(rr, v.y, g1);
    g2 = fmaf(rr, v.z, g2);
    g3 = fmaf(rr, v.w, g3);
  }
  const float d = Ds;
  float4 o;
  o.x = 1.f / (1.f + expf(-(g0 + d)));
  o.y = 1.f / (1.f + expf(-(g1 + d)));
  o.z = 1.f / (1.f + expf(-(g2 + d)));
  o.w = 1.f / (1.f + expf(-(g3 + d)));
  *(float4*)&out[(size_t)b * NPIX + p] = o;
}

// ---------------------------------------------------------------------------
extern "C" void kernel_launch(void* const* d_in, const int* in_sizes, int n_in,
                              void* d_out, int out_size, void* d_ws, size_t ws_size,
                              hipStream_t stream) {
  const float* x      = (const float*)d_in[0];
  const float* dw_w   = (const float*)d_in[1];
  const float* dw_b   = (const float*)d_in[2];
  const float* gn_w   = (const float*)d_in[3];
  const float* gn_b   = (const float*)d_in[4];
  const float* proj_w = (const float*)d_in[5];
  const float* proj_b = (const float*)d_in[6];
  float* out = (float*)d_out;

  const size_t P_BYTES = (size_t)16 * GG * NPIX * 4;     // fp32: 18,874,368 B
  float* P        = (float*)d_ws;
  float* partials = (float*)((char*)d_ws + P_BYTES);     // 1536*2 f32

  hipLaunchKernelGGL(k_main, dim3(16 * GG * YT), dim3(TPB), 0, stream,
                     x, dw_w, dw_b, gn_w, proj_w, P, partials);
  hipLaunchKernelGGL(k_out, dim3(16 * 9), dim3(256), 0, stream,
                     P, partials, dw_b, gn_w, gn_b, proj_w, proj_b, out);
}